// Round 1
// baseline (493.180 us; speedup 1.0000x reference)
//
#include <hip/hip_runtime.h>
#include <math.h>

#define NPTS 65536
#define DIM 64
#define NCODE 1024

// output layout (flat float32 concat, reference return order)
#define OFF_LOSS 0ull
#define OFF_Q    1ull
#define OFF_PERP 4194305ull
#define OFF_ENC  4194306ull
#define OFF_IDX  71303170ull

// ---------------- e2[k] = sum_d emb[k][d]^2 ----------------
__global__ __launch_bounds__(256) void vq_e2(const float* __restrict__ emb,
                                             float* __restrict__ e2) {
    int k = blockIdx.x * 256 + threadIdx.x;
    if (k >= NCODE) return;
    const float4* e4 = (const float4*)(emb + (size_t)k * DIM);
    float s = 0.f;
#pragma unroll
    for (int i = 0; i < DIM / 4; ++i) {
        float4 v = e4[i];
        s += v.x * v.x + v.y * v.y + v.z * v.z + v.w * v.w;
    }
    e2[k] = s;
}

// ---------------- main: argmin + q_ste + one-hot + partial loss + hist ----------------
__global__ __launch_bounds__(256) void vq_main(const float* __restrict__ in,
                                               const float* __restrict__ emb,
                                               const float* __restrict__ e2,
                                               float* __restrict__ out,
                                               float* __restrict__ loss_acc,
                                               unsigned int* __restrict__ hist) {
    int p = blockIdx.x * 256 + threadIdx.x;           // point id 0..65535
    int w = p & 63;
    int h = (p >> 6) & 63;
    int b = p >> 12;
    // BCHW: in[b][d][h][w], stride between d's = 64*64 = 4096 floats
    const float* xb = in + (size_t)b * (DIM * 4096) + h * 64 + w;

    float x[DIM];
#pragma unroll
    for (int d = 0; d < DIM; ++d) x[d] = xb[(size_t)d * 4096];

    float best = INFINITY;
    int bi = 0;
    // k, d are wave-uniform -> embedding loads should scalarize (s_load)
    for (int k = 0; k < NCODE; ++k) {
        const float* e = emb + (size_t)k * DIM;
        float a0 = 0.f, a1 = 0.f, a2 = 0.f, a3 = 0.f;
#pragma unroll
        for (int d = 0; d < DIM; d += 4) {
            a0 = fmaf(x[d + 0], e[d + 0], a0);
            a1 = fmaf(x[d + 1], e[d + 1], a1);
            a2 = fmaf(x[d + 2], e[d + 2], a2);
            a3 = fmaf(x[d + 3], e[d + 3], a3);
        }
        float dist = e2[k] - 2.0f * ((a0 + a1) + (a2 + a3));
        if (dist < best) { best = dist; bi = k; }   // strict '<' keeps first index (jnp.argmin)
    }

    // gather quantized row (divergent -> vector loads, L2-resident)
    const float4* eb4 = (const float4*)(emb + (size_t)bi * DIM);
    float* qb = out + OFF_Q + (size_t)b * (DIM * 4096) + h * 64 + w;
    float lsum = 0.f;
#pragma unroll
    for (int i = 0; i < DIM / 4; ++i) {
        float4 q = eb4[i];
        int d = i * 4;
        float d0 = q.x - x[d + 0];
        float d1 = q.y - x[d + 1];
        float d2 = q.z - x[d + 2];
        float d3 = q.w - x[d + 3];
        lsum = fmaf(d0, d0, lsum);
        lsum = fmaf(d1, d1, lsum);
        lsum = fmaf(d2, d2, lsum);
        lsum = fmaf(d3, d3, lsum);
        // straight-through estimator: x + (q - x), computed exactly like the reference
        qb[(size_t)(d + 0) * 4096] = x[d + 0] + d0;
        qb[(size_t)(d + 1) * 4096] = x[d + 1] + d1;
        qb[(size_t)(d + 2) * 4096] = x[d + 2] + d2;
        qb[(size_t)(d + 3) * 4096] = x[d + 3] + d3;
    }

    out[OFF_IDX + p] = (float)bi;
    out[OFF_ENC + (size_t)p * NCODE + bi] = 1.0f;   // encodings memset to 0 beforehand
    atomicAdd(&hist[bi], 1u);

    // wave64 reduce of lsum, one atomic per wave
    for (int off = 32; off > 0; off >>= 1)
        lsum += __shfl_down(lsum, off, 64);
    if ((threadIdx.x & 63) == 0) atomicAdd(loss_acc, lsum);
}

// ---------------- finalize: loss scalar + perplexity ----------------
__global__ __launch_bounds__(1024) void vq_finalize(const unsigned int* __restrict__ hist,
                                                    const float* __restrict__ loss_acc,
                                                    float* __restrict__ out) {
    int t = threadIdx.x;                       // 0..1023, one per code
    float c = (float)hist[t];
    float pv = c * (1.0f / (float)NPTS);
    float term = pv * logf(pv + 1e-10f);       // 0*log(1e-10) = 0, matches ref

    __shared__ float red[16];
    float s = term;
    for (int off = 32; off > 0; off >>= 1) s += __shfl_down(s, off, 64);
    if ((t & 63) == 0) red[t >> 6] = s;
    __syncthreads();
    if (t < 16) {
        float v = red[t];
        for (int off = 8; off > 0; off >>= 1) v += __shfl_down(v, off, 64);
        if (t == 0) {
            out[OFF_PERP] = expf(-v);
            out[OFF_LOSS] = 0.25f * loss_acc[0] * (1.0f / 4194304.0f);
        }
    }
}

extern "C" void kernel_launch(void* const* d_in, const int* in_sizes, int n_in,
                              void* d_out, int out_size, void* d_ws, size_t ws_size,
                              hipStream_t stream) {
    const float* in  = (const float*)d_in[0];   // (16,64,64,64) BCHW
    const float* emb = (const float*)d_in[1];   // (1024,64)
    float* out = (float*)d_out;

    // workspace layout: [0..15] loss accumulator (+pad), [16..1039] hist, [1040..2063] e2
    float* ws_f = (float*)d_ws;
    float* loss_acc = ws_f;
    unsigned int* hist = (unsigned int*)d_ws + 16;
    float* e2 = ws_f + 16 + NCODE;

    hipMemsetAsync(d_ws, 0, (16 + NCODE) * sizeof(float), stream);
    hipMemsetAsync(out + OFF_ENC, 0, (size_t)NPTS * NCODE * sizeof(float), stream);

    vq_e2<<<NCODE / 256, 256, 0, stream>>>(emb, e2);
    vq_main<<<NPTS / 256, 256, 0, stream>>>(in, emb, e2, out, loss_acc, hist);
    vq_finalize<<<1, 1024, 0, stream>>>(hist, loss_acc, out);
}

// Round 3
// 192.609 us; speedup vs baseline: 2.5605x; 2.5605x over previous
//
#include <hip/hip_runtime.h>
#include <math.h>

#define NPTS 65536
#define DIM 64
#define NCODE 1024

typedef float f32x2 __attribute__((ext_vector_type(2)));

// output layout (flat float32 concat, reference return order)
#define OFF_LOSS 0ull
#define OFF_Q    1ull
#define OFF_PERP 4194305ull
#define OFF_ENC  4194306ull
#define OFF_IDX  71303170ull

// ---------------- e2[k] = sum_d emb[k][d]^2 ----------------
__global__ __launch_bounds__(256) void vq_e2(const float* __restrict__ emb,
                                             float* __restrict__ e2) {
    int k = blockIdx.x * 256 + threadIdx.x;
    if (k >= NCODE) return;
    const float4* e4 = (const float4*)(emb + (size_t)k * DIM);
    float s = 0.f;
#pragma unroll
    for (int i = 0; i < DIM / 4; ++i) {
        float4 v = e4[i];
        s += v.x * v.x + v.y * v.y + v.z * v.z + v.w * v.w;
    }
    e2[k] = s;
}

// ---------------- main ----------------
// Block = 256 threads = 4 waves. Block owns 64 points (lane = point).
// Wave s scans codes [256s, 256s+256): full 64-dim dot per code, running argmin.
// Merge 4 candidates per point via LDS (slice order preserves first-min tie-break).
// Wave 0 epilogue: q_ste + loss (x[64] lives in wave 0's registers, static idx).
// All 4 waves then stream the 64x1024 one-hot block (nontemporal f32x2).
__global__ __launch_bounds__(256, 4) void vq_main(const float* __restrict__ in,
                                                  const float* __restrict__ emb,
                                                  const float* __restrict__ e2,
                                                  float* __restrict__ out,
                                                  float* __restrict__ loss_acc,
                                                  unsigned int* __restrict__ hist) {
    __shared__ float s_dist[4][64];
    __shared__ int   s_idx[4][64];
    __shared__ int   s_bi[64];

    const int tid  = threadIdx.x;
    const int lane = tid & 63;
    const int sl   = __builtin_amdgcn_readfirstlane(tid >> 6);  // wave slice 0..3 (uniform)

    const int p = blockIdx.x * 64 + lane;       // point id
    const int w = p & 63;
    const int h = (p >> 6) & 63;
    const int b = p >> 12;
    // BCHW: in[b][d][h][w], d-stride = 4096 floats
    const float* xb = in + (size_t)b * (DIM * 4096) + h * 64 + w;

    float x[DIM];
#pragma unroll
    for (int d = 0; d < DIM; ++d) x[d] = xb[(size_t)d * 4096];

    float best = INFINITY;
    int bi = 0;
    const int k0 = sl * 256;
    for (int kk = 0; kk < 256; ++kk) {
        const int k = k0 + kk;                   // wave-uniform -> scalar e loads
        const float* e = emb + (size_t)k * DIM;
        float a0 = 0.f, a1 = 0.f, a2 = 0.f, a3 = 0.f;
#pragma unroll
        for (int d = 0; d < DIM; d += 4) {
            a0 = fmaf(x[d + 0], e[d + 0], a0);
            a1 = fmaf(x[d + 1], e[d + 1], a1);
            a2 = fmaf(x[d + 2], e[d + 2], a2);
            a3 = fmaf(x[d + 3], e[d + 3], a3);
        }
        float dist = e2[k] - 2.0f * ((a0 + a1) + (a2 + a3));
        if (dist < best) { best = dist; bi = k; }  // strict '<': first-min within slice
    }

    s_dist[sl][lane] = best;
    s_idx[sl][lane]  = bi;
    __syncthreads();

    if (tid < 64) {   // wave 0 merges (ascending slice order keeps smallest index on ties)
        float bd = s_dist[0][tid];
        int  bix = s_idx[0][tid];
#pragma unroll
        for (int s2 = 1; s2 < 4; ++s2) {
            float d2 = s_dist[s2][tid];
            int   i2 = s_idx[s2][tid];
            if (d2 < bd) { bd = d2; bix = i2; }
        }
        s_bi[tid] = bix;
        out[OFF_IDX + p] = (float)bix;
        atomicAdd(&hist[bix], 1u);
    }
    __syncthreads();

    // ---- epilogue A (wave 0 only): q_ste + loss, all 64 dims, static indexing ----
    if (tid < 64) {
        const int mybi = s_bi[tid];
        const float* eq = emb + (size_t)mybi * DIM;
        float* qb = out + OFF_Q + (size_t)b * (DIM * 4096) + h * 64 + w;
        float lsum = 0.f;
#pragma unroll
        for (int d = 0; d < DIM; ++d) {
            float diff = eq[d] - x[d];
            lsum = fmaf(diff, diff, lsum);
            qb[(size_t)d * 4096] = x[d] + diff;   // exact STE form as reference
        }
        for (int off = 32; off > 0; off >>= 1)
            lsum += __shfl_down(lsum, off, 64);
        if (lane == 0) atomicAdd(loss_acc, lsum);
    }

    // ---- epilogue B (all threads): stream one-hot rows for points p0..p0+63 ----
    // Region: 64 rows x 1024 floats = 32768 f32x2, contiguous. 8B-aligned base.
    {
        f32x2* enc2 = (f32x2*)(out + OFF_ENC + (unsigned long long)blockIdx.x * 64 * NCODE);
#pragma unroll 8
        for (int i = 0; i < 128; ++i) {
            int j2 = tid + i * 256;          // 0..32767
            int pr = j2 >> 9;                // row (point within block)
            int c2 = j2 & 511;               // f32x2 column
            int tb = s_bi[pr];
            f32x2 v = (f32x2)(0.f, 0.f);
            if (c2 == (tb >> 1)) {
                if (tb & 1) v.y = 1.0f; else v.x = 1.0f;
            }
            __builtin_nontemporal_store(v, &enc2[j2]);
        }
    }
}

// ---------------- finalize: loss scalar + perplexity ----------------
__global__ __launch_bounds__(1024) void vq_finalize(const unsigned int* __restrict__ hist,
                                                    const float* __restrict__ loss_acc,
                                                    float* __restrict__ out) {
    int t = threadIdx.x;                       // 0..1023, one per code
    float c = (float)hist[t];
    float pv = c * (1.0f / (float)NPTS);
    float term = pv * logf(pv + 1e-10f);

    __shared__ float red[16];
    float s = term;
    for (int off = 32; off > 0; off >>= 1) s += __shfl_down(s, off, 64);
    if ((t & 63) == 0) red[t >> 6] = s;
    __syncthreads();
    if (t < 16) {
        float v = red[t];
        for (int off = 8; off > 0; off >>= 1) v += __shfl_down(v, off, 64);
        if (t == 0) {
            out[OFF_PERP] = expf(-v);
            out[OFF_LOSS] = 0.25f * loss_acc[0] * (1.0f / 4194304.0f);
        }
    }
}

extern "C" void kernel_launch(void* const* d_in, const int* in_sizes, int n_in,
                              void* d_out, int out_size, void* d_ws, size_t ws_size,
                              hipStream_t stream) {
    const float* in  = (const float*)d_in[0];   // (16,64,64,64) BCHW
    const float* emb = (const float*)d_in[1];   // (1024,64)
    float* out = (float*)d_out;

    // workspace: [0..15] loss accumulator, [16..1039] hist, [1040..2063] e2
    float* ws_f = (float*)d_ws;
    float* loss_acc = ws_f;
    unsigned int* hist = (unsigned int*)d_ws + 16;
    float* e2 = ws_f + 16 + NCODE;

    (void)hipMemsetAsync(d_ws, 0, (16 + NCODE) * sizeof(float), stream);

    vq_e2<<<NCODE / 256, 256, 0, stream>>>(emb, e2);
    vq_main<<<NPTS / 64, 256, 0, stream>>>(in, emb, e2, out, loss_acc, hist);
    vq_finalize<<<1, 1024, 0, stream>>>(hist, loss_acc, out);
}

// Round 4
// 173.123 us; speedup vs baseline: 2.8487x; 1.1126x over previous
//
#include <hip/hip_runtime.h>
#include <math.h>

#define NPTS 65536
#define DIM 64
#define NCODE 1024

typedef float f32x2 __attribute__((ext_vector_type(2)));
typedef float f32x4 __attribute__((ext_vector_type(4)));
typedef short bf16x8 __attribute__((ext_vector_type(8)));
typedef unsigned short u16x4 __attribute__((ext_vector_type(4)));

// output layout (flat float32 concat, reference return order)
#define OFF_LOSS 0ull
#define OFF_Q    1ull
#define OFF_PERP 4194305ull
#define OFF_ENC  4194306ull
#define OFF_IDX  71303170ull

__device__ __forceinline__ unsigned short bf16hi(float f) {
    unsigned u = __float_as_uint(f);
    unsigned r = u + 0x7FFFu + ((u >> 16) & 1u);   // RNE truncate to bf16
    return (unsigned short)(r >> 16);
}
__device__ __forceinline__ float bf16tof(unsigned short h) {
    return __uint_as_float(((unsigned)h) << 16);
}

// ---------------- emb fp32 -> (hi,lo) bf16 split, row-major (code, dim) ----------------
__global__ __launch_bounds__(256) void vq_ecvt(const float* __restrict__ emb,
                                               unsigned short* __restrict__ ehi,
                                               unsigned short* __restrict__ elo) {
    int t = blockIdx.x * 256 + threadIdx.x;        // 0..16383, one float4 each
    float4 v = ((const float4*)emb)[t];
    float vv[4] = {v.x, v.y, v.z, v.w};
    u16x4 hi, lo;
#pragma unroll
    for (int i = 0; i < 4; ++i) {
        unsigned short h = bf16hi(vv[i]);
        hi[i] = h;
        lo[i] = bf16hi(vv[i] - bf16tof(h));
    }
    *(u16x4*)(ehi + (size_t)t * 4) = hi;
    *(u16x4*)(elo + (size_t)t * 4) = lo;
}

// ---------------- e2[k] = sum_d emb[k][d]^2 (deterministic per-thread) ----------------
__global__ __launch_bounds__(256) void vq_e2(const float* __restrict__ emb,
                                             float* __restrict__ e2) {
    int k = blockIdx.x * 256 + threadIdx.x;
    if (k >= NCODE) return;
    const float4* e4 = (const float4*)(emb + (size_t)k * DIM);
    float s = 0.f;
#pragma unroll
    for (int i = 0; i < DIM / 4; ++i) {
        float4 v = e4[i];
        s += v.x * v.x + v.y * v.y + v.z * v.z + v.w * v.w;
    }
    e2[k] = s;
}

// ---------------- distance argmin via bf16-split MFMA ----------------
// Block = 4 waves, 64 points (one b,h row of w). Prologue: BCHW fp32 -> LDS
// transposed (point, dim) hi/lo bf16. Each wave scans 256 codes: A-frags
// resident (16 frags, reused 16x), B-frags straight from global (L2).
// dist = e2[c] - 2*(hi.hi + hi.lo + lo.hi). Packed-u64 lexicographic argmin.
__global__ __launch_bounds__(256, 3) void vq_dist(const float* __restrict__ in,
                                                  const unsigned short* __restrict__ ehi,
                                                  const unsigned short* __restrict__ elo,
                                                  const float* __restrict__ e2,
                                                  float* __restrict__ out,
                                                  int* __restrict__ idx_ws,
                                                  unsigned int* __restrict__ hist) {
    __shared__ __align__(16) unsigned short lds_hi[64][72];  // [point][dim], 144B row stride
    __shared__ __align__(16) unsigned short lds_lo[64][72];
    __shared__ unsigned long long cand[4][64];

    const int tid  = threadIdx.x;
    const int lane = tid & 63;
    const int wv   = __builtin_amdgcn_readfirstlane(tid >> 6);

    const int P0 = blockIdx.x * 64;
    const int b  = P0 >> 12;
    const int h  = (P0 >> 6) & 63;
    const float* base = in + (size_t)b * (DIM * 4096) + h * 64;

    // ---- prologue: load 64x64 fp32 tile (coalesced), split, transpose to LDS ----
    {
        int d  = tid >> 2;
        int wq = tid & 3;
        const float* rowp = base + (size_t)d * 4096 + wq * 16;
#pragma unroll
        for (int j = 0; j < 4; ++j) {
            float4 v = *(const float4*)(rowp + j * 4);
            float vv[4] = {v.x, v.y, v.z, v.w};
#pragma unroll
            for (int i = 0; i < 4; ++i) {
                int w = wq * 16 + j * 4 + i;
                unsigned short hb = bf16hi(vv[i]);
                lds_hi[w][d] = hb;
                lds_lo[w][d] = bf16hi(vv[i] - bf16tof(hb));
            }
        }
    }
    __syncthreads();

    // ---- A fragments (resident): A[m][k], m=lane&15, k=(lane>>4)*8+j ----
    const int m15 = lane & 15;
    const int kb  = (lane >> 4) * 8;
    bf16x8 Ahi[4][2], Alo[4][2];
#pragma unroll
    for (int pt = 0; pt < 4; ++pt) {
        int p = pt * 16 + m15;
        Ahi[pt][0] = *(const bf16x8*)&lds_hi[p][kb];
        Ahi[pt][1] = *(const bf16x8*)&lds_hi[p][kb + 32];
        Alo[pt][0] = *(const bf16x8*)&lds_lo[p][kb];
        Alo[pt][1] = *(const bf16x8*)&lds_lo[p][kb + 32];
    }

    float best[4][4];
    int   bestk[4][4];
#pragma unroll
    for (int pt = 0; pt < 4; ++pt) {
#pragma unroll
        for (int r = 0; r < 4; ++r) { best[pt][r] = INFINITY; bestk[pt][r] = 0; }
    }

    const int c0w = wv * 256;                 // this wave's code slice (ascending)
    for (int ct = 0; ct < 16; ++ct) {
        const int code = c0w + ct * 16 + m15; // B col n = lane&15
        const unsigned short* eh = ehi + (size_t)code * 64 + kb;
        const unsigned short* el = elo + (size_t)code * 64 + kb;
        bf16x8 Bhi0 = *(const bf16x8*)eh;
        bf16x8 Bhi1 = *(const bf16x8*)(eh + 32);
        bf16x8 Blo0 = *(const bf16x8*)el;
        bf16x8 Blo1 = *(const bf16x8*)(el + 32);
        float e2v = e2[code];

#pragma unroll
        for (int pt = 0; pt < 4; ++pt) {
            f32x4 acc = {0.f, 0.f, 0.f, 0.f};
            acc = __builtin_amdgcn_mfma_f32_16x16x32_bf16(Ahi[pt][0], Bhi0, acc, 0, 0, 0);
            acc = __builtin_amdgcn_mfma_f32_16x16x32_bf16(Ahi[pt][1], Bhi1, acc, 0, 0, 0);
            acc = __builtin_amdgcn_mfma_f32_16x16x32_bf16(Ahi[pt][0], Blo0, acc, 0, 0, 0);
            acc = __builtin_amdgcn_mfma_f32_16x16x32_bf16(Ahi[pt][1], Blo1, acc, 0, 0, 0);
            acc = __builtin_amdgcn_mfma_f32_16x16x32_bf16(Alo[pt][0], Bhi0, acc, 0, 0, 0);
            acc = __builtin_amdgcn_mfma_f32_16x16x32_bf16(Alo[pt][1], Bhi1, acc, 0, 0, 0);
#pragma unroll
            for (int r = 0; r < 4; ++r) {
                float dist = fmaf(-2.0f, acc[r], e2v);
                if (dist < best[pt][r]) { best[pt][r] = dist; bestk[pt][r] = code; }
            }
        }
    }

    // ---- per-wave cross-lane argmin: lexicographic (dist, code) over 16 cols ----
#pragma unroll
    for (int pt = 0; pt < 4; ++pt) {
#pragma unroll
        for (int r = 0; r < 4; ++r) {
            unsigned u = __float_as_uint(best[pt][r]);
            u = (u & 0x80000000u) ? ~u : (u | 0x80000000u);   // monotone f32->u32
            unsigned long long key = ((unsigned long long)u << 32) | (unsigned)bestk[pt][r];
#pragma unroll
            for (int sm = 1; sm < 16; sm <<= 1) {
                unsigned long long o = __shfl_xor(key, sm, 16);
                key = (o < key) ? o : key;
            }
            if (m15 == 0) cand[wv][pt * 16 + (lane >> 4) * 4 + r] = key;
        }
    }
    __syncthreads();

    if (tid < 64) {
        unsigned long long k0 = cand[0][tid];
#pragma unroll
        for (int s = 1; s < 4; ++s) {
            unsigned long long o = cand[s][tid];
            if (o < k0) k0 = o;
        }
        int idx = (int)(k0 & 0xFFFFFFFFull);
        idx_ws[P0 + tid] = idx;
        out[OFF_IDX + P0 + tid] = (float)idx;
        atomicAdd(&hist[idx], 1u);
    }
}

// ---------------- streaming outputs: q_ste + loss + one-hot ----------------
__global__ __launch_bounds__(256) void vq_stream(const float* __restrict__ in,
                                                 const float* __restrict__ emb,
                                                 const int* __restrict__ idx_ws,
                                                 float* __restrict__ out,
                                                 float* __restrict__ loss_acc) {
    __shared__ int s_idx[64];
    const int tid = threadIdx.x;
    const int P0  = blockIdx.x * 64;
    if (tid < 64) s_idx[tid] = idx_ws[P0 + tid];
    __syncthreads();

    const int b  = P0 >> 12;
    const int h  = (P0 >> 6) & 63;
    const int w  = tid & 63;
    const int dg = tid >> 6;                       // wave id = d-group
    const int myidx = s_idx[w];
    const float* eq = emb + (size_t)myidx * DIM;
    const float* xb = in + ((size_t)b * 64 + dg * 16) * 4096 + h * 64 + w;
    float* qb = out + OFF_Q + ((size_t)b * 64 + dg * 16) * 4096 + h * 64 + w;

    float lsum = 0.f;
#pragma unroll
    for (int dd = 0; dd < 16; ++dd) {
        float x = xb[(size_t)dd * 4096];
        float diff = eq[dg * 16 + dd] - x;
        lsum = fmaf(diff, diff, lsum);
        qb[(size_t)dd * 4096] = x + diff;          // exact STE form as reference
    }
    for (int off = 32; off > 0; off >>= 1) lsum += __shfl_down(lsum, off, 64);
    if ((tid & 63) == 0) atomicAdd(loss_acc, lsum);

    // one-hot rows for the block's 64 points (nontemporal f32x2 stream)
    f32x2* enc2 = (f32x2*)(out + OFF_ENC + (unsigned long long)blockIdx.x * 64 * NCODE);
#pragma unroll 8
    for (int i = 0; i < 128; ++i) {
        int j2 = tid + i * 256;
        int pr = j2 >> 9;
        int c2 = j2 & 511;
        int tb = s_idx[pr];
        f32x2 v = {0.f, 0.f};
        if (c2 == (tb >> 1)) { if (tb & 1) v.y = 1.0f; else v.x = 1.0f; }
        __builtin_nontemporal_store(v, &enc2[j2]);
    }
}

// ---------------- finalize: loss scalar + perplexity ----------------
__global__ __launch_bounds__(1024) void vq_finalize(const unsigned int* __restrict__ hist,
                                                    const float* __restrict__ loss_acc,
                                                    float* __restrict__ out) {
    int t = threadIdx.x;
    float c = (float)hist[t];
    float pv = c * (1.0f / (float)NPTS);
    float term = pv * logf(pv + 1e-10f);

    __shared__ float red[16];
    float s = term;
    for (int off = 32; off > 0; off >>= 1) s += __shfl_down(s, off, 64);
    if ((t & 63) == 0) red[t >> 6] = s;
    __syncthreads();
    if (t < 16) {
        float v = red[t];
        for (int off = 8; off > 0; off >>= 1) v += __shfl_down(v, off, 64);
        if (t == 0) {
            out[OFF_PERP] = expf(-v);
            out[OFF_LOSS] = 0.25f * loss_acc[0] * (1.0f / 4194304.0f);
        }
    }
}

extern "C" void kernel_launch(void* const* d_in, const int* in_sizes, int n_in,
                              void* d_out, int out_size, void* d_ws, size_t ws_size,
                              hipStream_t stream) {
    const float* in  = (const float*)d_in[0];   // (16,64,64,64) BCHW
    const float* emb = (const float*)d_in[1];   // (1024,64)
    float* out = (float*)d_out;

    // ws layout (floats unless noted):
    // [0..15] loss_acc | [16..1039] hist u32 | [1040..2063] e2
    // [2064..67599] idx i32 | then ehi ushort[65536], elo ushort[65536]
    float* ws_f = (float*)d_ws;
    float* loss_acc = ws_f;
    unsigned int* hist = (unsigned int*)d_ws + 16;
    float* e2 = ws_f + 16 + NCODE;
    int* idx_ws = (int*)d_ws + 16 + NCODE + NCODE;
    unsigned short* ehi = (unsigned short*)(ws_f + 16 + 2 * NCODE + NPTS);
    unsigned short* elo = ehi + (size_t)NCODE * DIM;

    (void)hipMemsetAsync(d_ws, 0, (16 + NCODE) * sizeof(float), stream);

    vq_ecvt<<<(NCODE * DIM / 4) / 256, 256, 0, stream>>>(emb, ehi, elo);
    vq_e2<<<NCODE / 256, 256, 0, stream>>>(emb, e2);
    vq_dist<<<NPTS / 64, 256, 0, stream>>>(in, ehi, elo, e2, out, idx_ws, hist);
    vq_stream<<<NPTS / 64, 256, 0, stream>>>(in, emb, idx_ws, out, loss_acc);
    vq_finalize<<<1, 1024, 0, stream>>>(hist, loss_acc, out);
}